// Round 6
// baseline (287.679 us; speedup 1.0000x reference)
//
#include <hip/hip_runtime.h>
#include <hip/hip_bf16.h>

#define HID 128

typedef __attribute__((ext_vector_type(8))) short short8;   // 8 x bf16 (4 VGPRs)
typedef __attribute__((ext_vector_type(4))) float f32x4;    // MFMA C/D

static __device__ __forceinline__ short f2bf(float x) {
    __hip_bfloat16 h = __float2bfloat16(x);   // RNE
    return *reinterpret_cast<short*>(&h);
}

// ---------------------------------------------------------------------------
// K1: the two INDEPENDENT 128x128 products in one launch, plus the bias
// chain parallelized over its 128 outputs.
//   blocks 0..127   : P_left  = Wo  @ W_mo      (row b)
//   blocks 128..255 : P_right = Wiv @ Wv        (row b-128)
//   block  256      : cv = 0.5*(Wo@(W_mo@(Wiv@bv + biv) + b_mo) + bo)
// ---------------------------------------------------------------------------
__global__ void prep_products(const float* __restrict__ Wo,
                              const float* __restrict__ W_mo,
                              const float* __restrict__ Wiv,
                              const float* __restrict__ Wv,
                              const float* __restrict__ bv,
                              const float* __restrict__ biv,
                              const float* __restrict__ b_mo,
                              const float* __restrict__ bo,
                              float* __restrict__ Pl,
                              float* __restrict__ Pr,
                              float* __restrict__ cv)
{
    const int j = threadIdx.x;
    const int b = blockIdx.x;
    __shared__ float sh[HID];

    if (b < 256) {
        const float* A = (b < 128) ? Wo   : Wiv;
        const float* B = (b < 128) ? W_mo : Wv;
        float*       C = (b < 128) ? Pl   : Pr;
        const int i = b & 127;
        sh[j] = A[i * HID + j];
        __syncthreads();
        float s = 0.f;
        #pragma unroll 16
        for (int k = 0; k < HID; ++k) s += sh[k] * B[k * HID + j];
        C[i * HID + j] = s;
    } else {
        // bias chain: 3 matvecs, each parallel over the 128 outputs.
        sh[j] = bv[j];
        __syncthreads();
        float t = biv[j];
        #pragma unroll 16
        for (int k = 0; k < HID; ++k) t += Wiv[j * HID + k] * sh[k];
        __syncthreads(); sh[j] = t; __syncthreads();
        t = b_mo[j];
        #pragma unroll 16
        for (int k = 0; k < HID; ++k) t += W_mo[j * HID + k] * sh[k];
        __syncthreads(); sh[j] = t; __syncthreads();
        t = bo[j];
        #pragma unroll 16
        for (int k = 0; k < HID; ++k) t += Wo[j * HID + k] * sh[k];
        cv[j] = 0.5f * t;
    }
}

// ---------------------------------------------------------------------------
// K2: M' = bf16( I + 0.5 * P_left @ P_right )   (row-major [n][k])
// ---------------------------------------------------------------------------
__global__ void prep_final(const float* __restrict__ Pl,
                           const float* __restrict__ Pr,
                           __hip_bfloat16* __restrict__ Mb)
{
    const int i = blockIdx.x, j = threadIdx.x;
    __shared__ float sh[HID];
    sh[j] = Pl[i * HID + j];
    __syncthreads();
    float s = 0.f;
    #pragma unroll 16
    for (int k = 0; k < HID; ++k) s += sh[k] * Pr[k * HID + j];
    Mb[i * HID + j] = __float2bfloat16(((i == j) ? 1.0f : 0.0f) + 0.5f * s);
}

// ---------------------------------------------------------------------------
// Main: out[e][:] = ea[e][:] @ M'^T + cv      (fp32 in/out, bf16 MFMA)
//
// R6 analysis: R0-R5 were all capped ~2.4 TB/s regardless of occupancy (R2)
// and pipeline depth (R5) while fillBuffer hits 6.6 TB/s -> fixed-rate
// shared-resource saturation. Accounting: in R5 all 4 waves of a block read
// the SAME 8KB fp32 tile from LDS (edges = shared B-operand; waves differed
// only in register-resident M'-columns): 8KB write + 32KB read = 40KB LDS
// traffic per 16-edge tile ~= 450 cy of the 128 B/cy LDS port per
// block-iter x 6 blocks ~= 90% port saturation. THE LDS PIPE WAS THE WALL.
//
// Fix: per-WAVE independent tiles. Each wave holds the FULL M' in registers
// (Mfrag[8][4] = 128 VGPR), owns a private LDS double-buffer (2 x 8KB), and
// computes all 128 output cols of its own 16 edges: LDS traffic per tile
// 8KB write + 8KB read (2.5x cut), DS instrs 40 -> 16/tile, and ZERO
// barriers -- sync is per-wave counted vmcnt only (steady state vmcnt(16):
// stage_cur retired, store_prev + stage_next stay in flight).
// ~210 VGPR -> 2 waves/SIMD; 64KB LDS/block -> 2 blocks/CU = 8 waves/CU,
// each with 16KB in flight (MLP >> Little's-law need for 6.3 TB/s).
// ---------------------------------------------------------------------------
__global__ __launch_bounds__(256) void edge_gemm(
    const float* __restrict__ ea,
    const __hip_bfloat16* __restrict__ Mb,   // [128][128] bf16: M'[n][k]
    const float* __restrict__ cvec,          // [128] = 0.5*c
    float* __restrict__ out,
    int E, int numTiles, int nwaves)
{
    __shared__ __align__(16) float lds[4][2][2048];   // per wave: 2 x 8 KB

    const int lane = threadIdx.x & 63;
    const int wv   = threadIdx.x >> 6;
    const int q    = lane >> 4;      // 0..3
    const int c    = lane & 15;      // 0..15

    // Full M' in registers: lane (q,c) holds M'[nt*16 + c][kk*32 + q*8 .. +7]
    short8 Mfrag[8][4];
    #pragma unroll
    for (int nt = 0; nt < 8; ++nt) {
        const __hip_bfloat16* mp = Mb + (size_t)(nt * 16 + c) * HID + q * 8;
        #pragma unroll
        for (int kk = 0; kk < 4; ++kk)
            Mfrag[nt][kk] = *reinterpret_cast<const short8*>(mp + kk * 32);
    }
    // Bias as accumulator init: acc[nt][r] <-> out col nt*16 + q*4 + r
    f32x4 cvp[8];
    #pragma unroll
    for (int nt = 0; nt < 8; ++nt)
        cvp[nt] = *reinterpret_cast<const f32x4*>(cvec + nt * 16 + q * 4);

    int t = blockIdx.x * 4 + wv;     // global wave id = first tile
    if (t >= numTiles) return;

    // ds_read addressing (same swizzle scheme as R3/R5, HW-validated):
    // ea[row c][byte kk*128 + q*32 + h*16] lives at LDS byte
    // c*512 + ((kk*128 + q*32 + h*16) ^ ((c&7)<<4)); XOR fields disjoint.
    const int swz   = (c & 7) << 4;
    const int rbase = c * 512 + ((q * 32) ^ (swz & 0x60));
    const int hx    = swz & 16;

    float* bufA = &lds[wv][0][0];
    float* bufB = &lds[wv][1][0];

    // Stage one 16x512B tile: 8 global_load_lds width-16, ALL issued by the
    // owning wave. Instr i fills LDS bytes [i*1024, i*1024+1024) linearly
    // (HW: uniform base + lane*16). Source for linear pos p = i*1024+lane*16:
    //   r = p>>9 (tile row), b = (p&511) ^ ((r&7)<<4)   (pre-swizzle).
    auto stage = [&](float* buf, int edge0) {
        #pragma unroll
        for (int i = 0; i < 8; ++i) {
            const int r = i * 2 + (lane >> 5);
            const int b = ((lane & 31) * 16) ^ ((r & 7) << 4);
            int grow = edge0 + r; if (grow > E - 1) grow = E - 1;
            const char* src = (const char*)ea + (size_t)grow * 512 + b;
            float* dst = buf + i * 256;   // wave-uniform LDS base
            __builtin_amdgcn_global_load_lds(
                (const __attribute__((address_space(1))) void*)src,
                (__attribute__((address_space(3))) void*)dst,
                16, 0, 0);
        }
    };

    // Read tile once, 32 MFMA (8 n-tiles x 4 kk), 8 contiguous f32x4 stores.
    auto compute_store = [&](const float* buf, int tt) {
        f32x4 acc[8];
        #pragma unroll
        for (int nt = 0; nt < 8; ++nt) acc[nt] = cvp[nt];
        const char* lb = (const char*)buf;
        #pragma unroll
        for (int kk = 0; kk < 4; ++kk) {
            const float4 f0 = *reinterpret_cast<const float4*>(lb + rbase + kk * 128 + hx);
            const float4 f1 = *reinterpret_cast<const float4*>(lb + rbase + kk * 128 + (16 ^ hx));
            short8 v;
            v[0] = f2bf(f0.x); v[1] = f2bf(f0.y); v[2] = f2bf(f0.z); v[3] = f2bf(f0.w);
            v[4] = f2bf(f1.x); v[5] = f2bf(f1.y); v[6] = f2bf(f1.z); v[7] = f2bf(f1.w);
            #pragma unroll
            for (int nt = 0; nt < 8; ++nt)
                acc[nt] = __builtin_amdgcn_mfma_f32_16x16x32_bf16(Mfrag[nt][kk], v, acc[nt], 0, 0, 0);
        }
        const int orow = tt * 16 + c;
        if (orow < E) {
            float* op = out + (size_t)orow * HID + q * 4;
            #pragma unroll
            for (int nt = 0; nt < 8; ++nt)
                *reinterpret_cast<f32x4*>(op + nt * 16) = acc[nt];
        }
    };

    // Prologue: stage tile t (bufA) and, if present, tile t+nwaves (bufB).
    stage(bufA, t * 16);
    const int t2 = t + nwaves;
    const bool has2 = (t2 < numTiles);
    if (has2) stage(bufB, t2 * 16);

    // Iteration 0: wait for bufA's 8 stage ops (bufB's 8 may stay in flight).
    if (has2) { asm volatile("s_waitcnt vmcnt(8)" ::: "memory"); }
    else      { asm volatile("s_waitcnt vmcnt(0)" ::: "memory"); }
    __builtin_amdgcn_sched_barrier(0);
    compute_store(bufA, t);
    if (!has2) return;

    float* curb = bufB;
    float* othb = bufA;
    t = t2;
    while (true) {
        const int tn = t + nwaves;
        const bool has_next = (tn < numTiles);

        // othb was read last iteration (its ds_reads retired via lgkmcnt
        // before the MFMAs consumed them) -> safe to restage.
        if (has_next) stage(othb, tn * 16);

        // Per-wave queue (oldest first): stage_cur(8), store_prev(8),
        // [stage_next(8)]. vmcnt(16) retires stage_cur only; store_prev and
        // stage_next stay in flight. Tail (no stage_next): vmcnt(8).
        if (has_next) { asm volatile("s_waitcnt vmcnt(16)" ::: "memory"); }
        else          { asm volatile("s_waitcnt vmcnt(8)"  ::: "memory"); }
        __builtin_amdgcn_sched_barrier(0);

        compute_store(curb, t);

        if (!has_next) break;
        float* tmp = curb; curb = othb; othb = tmp;
        t = tn;
    }
}

// ---------------------------------------------------------------------------
// Inputs (setup_inputs order, all float32; edge_index int64 — DEAD):
//  0 edge_attr  1 node_features(DEAD)  2 regime_probs(DEAD)
//  3 Wq 4 bq 5 Wk 6 bk (DEAD: softmax over singleton seq = 1 => att = v2)
//  7 Wv 8 bv  9 W_in[3*128,128] 10 b_in[384] (only value third live)
// 11 W_mo 12 b_mo 13 Wo 14 bo 15 edge_index(DEAD)
// out = ea @ (I + 0.5*Wo@W_mo@Wiv@Wv)^T + 0.5*c
// ---------------------------------------------------------------------------
extern "C" void kernel_launch(void* const* d_in, const int* in_sizes, int n_in,
                              void* d_out, int out_size, void* d_ws, size_t ws_size,
                              hipStream_t stream) {
    const float* Wv   = (const float*)d_in[7];
    const float* bv   = (const float*)d_in[8];
    const float* W_in = (const float*)d_in[9];
    const float* b_in = (const float*)d_in[10];
    const float* W_mo = (const float*)d_in[11];
    const float* b_mo = (const float*)d_in[12];
    const float* Wo   = (const float*)d_in[13];
    const float* bo   = (const float*)d_in[14];
    const float* Wiv  = W_in + 2 * HID * HID;   // value third of packed in-proj
    const float* biv  = b_in + 2 * HID;

    char* ws = (char*)d_ws;
    float*          Pl = (float*)(ws);                    // 64 KB
    float*          Pr = (float*)(ws + 65536);            // 64 KB
    __hip_bfloat16* Mb = (__hip_bfloat16*)(ws + 131072);  // 32 KB
    float*          cv = (float*)(ws + 163840);           // 512 B

    const int E = in_sizes[0] / HID;
    const int numTiles = (E + 15) / 16;

    // 512 blocks x 4 waves = 2048 waves: exactly 2 blocks/CU resident
    // (64 KB LDS, ~210 VGPR -> 2 waves/SIMD), persistent-style.
    const int nblocks = 512;
    const int nwaves  = nblocks * 4;

    prep_products<<<dim3(257), dim3(HID), 0, stream>>>(
        Wo, W_mo, Wiv, Wv, bv, biv, b_mo, bo, Pl, Pr, cv);
    prep_final<<<dim3(HID), dim3(HID), 0, stream>>>(Pl, Pr, Mb);

    edge_gemm<<<dim3(nblocks), dim3(256), 0, stream>>>(
        (const float*)d_in[0], Mb, cv, (float*)d_out, E, numTiles, nwaves);
}

// Round 7
// 278.739 us; speedup vs baseline: 1.0321x; 1.0321x over previous
//
#include <hip/hip_runtime.h>
#include <hip/hip_bf16.h>

#define HID 128

typedef __attribute__((ext_vector_type(8))) short short8;   // 8 x bf16 (4 VGPRs)
typedef __attribute__((ext_vector_type(4))) float f32x4;    // MFMA C/D

static __device__ __forceinline__ short f2bf(float x) {
    __hip_bfloat16 h = __float2bfloat16(x);   // RNE
    return *reinterpret_cast<short*>(&h);
}

// ---------------------------------------------------------------------------
// K1: the two INDEPENDENT 128x128 products in one launch, plus the bias
// chain parallelized over its 128 outputs.
//   blocks 0..127   : P_left  = Wo  @ W_mo      (row b)
//   blocks 128..255 : P_right = Wiv @ Wv        (row b-128)
//   block  256      : cv = 0.5*(Wo@(W_mo@(Wiv@bv + biv) + b_mo) + bo)
// ---------------------------------------------------------------------------
__global__ void prep_products(const float* __restrict__ Wo,
                              const float* __restrict__ W_mo,
                              const float* __restrict__ Wiv,
                              const float* __restrict__ Wv,
                              const float* __restrict__ bv,
                              const float* __restrict__ biv,
                              const float* __restrict__ b_mo,
                              const float* __restrict__ bo,
                              float* __restrict__ Pl,
                              float* __restrict__ Pr,
                              float* __restrict__ cv)
{
    const int j = threadIdx.x;
    const int b = blockIdx.x;
    __shared__ float sh[HID];

    if (b < 256) {
        const float* A = (b < 128) ? Wo   : Wiv;
        const float* B = (b < 128) ? W_mo : Wv;
        float*       C = (b < 128) ? Pl   : Pr;
        const int i = b & 127;
        sh[j] = A[i * HID + j];
        __syncthreads();
        float s = 0.f;
        #pragma unroll 16
        for (int k = 0; k < HID; ++k) s += sh[k] * B[k * HID + j];
        C[i * HID + j] = s;
    } else {
        // bias chain: 3 matvecs, each parallel over the 128 outputs.
        sh[j] = bv[j];
        __syncthreads();
        float t = biv[j];
        #pragma unroll 16
        for (int k = 0; k < HID; ++k) t += Wiv[j * HID + k] * sh[k];
        __syncthreads(); sh[j] = t; __syncthreads();
        t = b_mo[j];
        #pragma unroll 16
        for (int k = 0; k < HID; ++k) t += W_mo[j * HID + k] * sh[k];
        __syncthreads(); sh[j] = t; __syncthreads();
        t = bo[j];
        #pragma unroll 16
        for (int k = 0; k < HID; ++k) t += Wo[j * HID + k] * sh[k];
        cv[j] = 0.5f * t;
    }
}

// ---------------------------------------------------------------------------
// K2: M' = bf16( I + 0.5 * P_left @ P_right )   (row-major [n][k])
// ---------------------------------------------------------------------------
__global__ void prep_final(const float* __restrict__ Pl,
                           const float* __restrict__ Pr,
                           __hip_bfloat16* __restrict__ Mb)
{
    const int i = blockIdx.x, j = threadIdx.x;
    __shared__ float sh[HID];
    sh[j] = Pl[i * HID + j];
    __syncthreads();
    float s = 0.f;
    #pragma unroll 16
    for (int k = 0; k < HID; ++k) s += sh[k] * Pr[k * HID + j];
    Mb[i * HID + j] = __float2bfloat16(((i == j) ? 1.0f : 0.0f) + 0.5f * s);
}

// ---------------------------------------------------------------------------
// Main: out[e][:] = ea[e][:] @ M'^T + cv      (fp32 in/out, bf16 MFMA)
//
// R7 analysis: per-CU total memory rate pinned at ~5 B/cy across SIX
// structural variants (register-scatter, occupancy 2x, LDS depth-2/3,
// wave-private no-barrier) while fillBuffer does 26 B/cy and float4-copy
// 10.2 B/cy on the same chip. The one axis never tested: all staged
// variants read via global_load_lds (LDS-DMA engine). Theory: the per-CU
// DMA queue is shallow (~2KB in flight -> 2KB/900cy ~= 2.3 B/cy read ==
// measured). Fix: dense REGISTER loads (m13-copy pattern, proven 6.3TB/s):
// thread tid loads bytes [tid*32, tid*32+32) of the block's 8KB tile ->
// 2 x ds_write_b128 into the proven swizzled LDS image -> raw s_barrier
// with lgkmcnt(0) ONLY (no vmcnt drain; compiler manages load->ds_write
// waits minimally). Double-buffered LDS, 2-deep register prefetch with
// statically-named slots (no runtime-indexed reg arrays).
// ---------------------------------------------------------------------------
__global__ __launch_bounds__(256) void edge_gemm(
    const float* __restrict__ ea,
    const __hip_bfloat16* __restrict__ Mb,   // [128][128] bf16: M'[n][k]
    const float* __restrict__ cvec,          // [128] = 0.5*c
    float* __restrict__ out,
    int E, int numTiles)
{
    __shared__ __align__(16) float lds[2][2048];   // 2 x 16 rows x 512 B

    const int lane  = threadIdx.x & 63;
    const int wv    = threadIdx.x >> 6;
    const int q     = lane >> 4;      // 0..3
    const int c     = lane & 15;      // 0..15
    const int ncol0 = wv * 32;        // this wave's 32 output cols

    // A-frag: lane (q,c) holds M'[ncol0 + nt*16 + c][kk*32 + q*8 .. +7]
    short8 Mfrag[2][4];
    #pragma unroll
    for (int nt = 0; nt < 2; ++nt) {
        const __hip_bfloat16* mp = Mb + (size_t)(ncol0 + nt * 16 + c) * HID + q * 8;
        #pragma unroll
        for (int kk = 0; kk < 4; ++kk)
            Mfrag[nt][kk] = *reinterpret_cast<const short8*>(mp + kk * 32);
    }
    // Bias as accumulator init: acc[nt][r] <-> out col ncol0 + nt*16 + q*4 + r
    f32x4 cvp[2];
    #pragma unroll
    for (int nt = 0; nt < 2; ++nt)
        cvp[nt] = *reinterpret_cast<const f32x4*>(cvec + ncol0 + nt * 16 + q * 4);

    int t = blockIdx.x;
    if (t >= numTiles) return;
    const int G = gridDim.x;

    // Dense-load addressing: thread tid covers global bytes
    // [tile_base + tid*32, +32) = row tid>>4, row-bytes (tid&15)*32 .. +32.
    const int ldrow = threadIdx.x >> 4;         // 0..15
    const int ldoff = (threadIdx.x & 15) * 32;  // 32B-aligned byte in row
    // ds_write: global (r, b) lands at LDS byte r*512 + (b ^ ((r&7)<<4)).
    const int wsw  = (ldrow & 7) << 4;
    const int wad0 = ldrow * 512 + (ldoff ^ wsw);        // for bytes [b0,b0+16)
    const int wad1 = wad0 ^ 16;                          // for bytes [b0+16,b0+32)

    // ds_read fragment addressing (proven in R3/R5/R6):
    // ea[row c][byte kk*128 + q*32 + h*16] at LDS byte
    // c*512 + ((kk*128 + q*32 + h*16) ^ ((c&7)<<4)); XOR fields disjoint.
    const int swz   = (c & 7) << 4;
    const int rbase = c * 512 + ((q * 32) ^ (swz & 0x60));
    const int hx    = swz & 16;

    auto load_tile = [&](int tt, float4& r0, float4& r1) {
        int row = tt * 16 + ldrow; if (row > E - 1) row = E - 1;
        const char* p = (const char*)ea + (size_t)row * 512 + ldoff;
        r0 = *reinterpret_cast<const float4*>(p);
        r1 = *reinterpret_cast<const float4*>(p + 16);
    };
    auto write_tile = [&](int buf, const float4& r0, const float4& r1) {
        char* lb = (char*)&lds[buf][0];
        *reinterpret_cast<float4*>(lb + wad0) = r0;
        *reinterpret_cast<float4*>(lb + wad1) = r1;
    };
    // lgkmcnt(0): my 2 ds_writes complete (LDS physically shared -> visible);
    // then block barrier. NO vmcnt here: prefetch loads stay in flight.
    auto sync = [&]() {
        __builtin_amdgcn_sched_barrier(0);
        asm volatile("s_waitcnt lgkmcnt(0)" ::: "memory");
        __builtin_amdgcn_s_barrier();
        __builtin_amdgcn_sched_barrier(0);
    };
    auto compute_store = [&](int buf, int tt) {
        const char* lb = (const char*)&lds[buf][0];
        f32x4 acc[2] = { cvp[0], cvp[1] };
        #pragma unroll
        for (int kk = 0; kk < 4; ++kk) {
            const float4 f0 = *reinterpret_cast<const float4*>(lb + rbase + kk * 128 + hx);
            const float4 f1 = *reinterpret_cast<const float4*>(lb + rbase + kk * 128 + (16 ^ hx));
            short8 v;
            v[0] = f2bf(f0.x); v[1] = f2bf(f0.y); v[2] = f2bf(f0.z); v[3] = f2bf(f0.w);
            v[4] = f2bf(f1.x); v[5] = f2bf(f1.y); v[6] = f2bf(f1.z); v[7] = f2bf(f1.w);
            acc[0] = __builtin_amdgcn_mfma_f32_16x16x32_bf16(Mfrag[0][kk], v, acc[0], 0, 0, 0);
            acc[1] = __builtin_amdgcn_mfma_f32_16x16x32_bf16(Mfrag[1][kk], v, acc[1], 0, 0, 0);
        }
        const int orow = tt * 16 + c;
        if (orow < E) {
            float* op = out + (size_t)orow * HID + ncol0 + q * 4;
            *reinterpret_cast<f32x4*>(op)      = acc[0];
            *reinterpret_cast<f32x4*>(op + 16) = acc[1];
        }
    };

    // 2-deep register prefetch, statically-named slots A/B (no runtime
    // reg-array indexing). Even tiles use slot A/buf0, odd use slot B/buf1.
    float4 a0, a1, b0, b1;
    load_tile(t, a0, a1);
    bool hB = (t + G < numTiles);
    if (hB) load_tile(t + G, b0, b1);

    while (true) {
        // even iter: tile t (slot A -> buf0)
        write_tile(0, a0, a1);
        if (t + 2 * G < numTiles) load_tile(t + 2 * G, a0, a1);  // refill A
        sync();
        compute_store(0, t);
        if (!hB) break;

        // odd iter: tile t+G (slot B -> buf1)
        write_tile(1, b0, b1);
        if (t + 3 * G < numTiles) load_tile(t + 3 * G, b0, b1);  // refill B
        sync();
        compute_store(1, t + G);

        t += 2 * G;
        if (t >= numTiles) break;       // slot A holds tile t iff t valid
        hB = (t + G < numTiles);        // slot B holds tile t+G iff hB
    }
}

// ---------------------------------------------------------------------------
// Inputs (setup_inputs order, all float32; edge_index int64 — DEAD):
//  0 edge_attr  1 node_features(DEAD)  2 regime_probs(DEAD)
//  3 Wq 4 bq 5 Wk 6 bk (DEAD: softmax over singleton seq = 1 => att = v2)
//  7 Wv 8 bv  9 W_in[3*128,128] 10 b_in[384] (only value third live)
// 11 W_mo 12 b_mo 13 Wo 14 bo 15 edge_index(DEAD)
// out = ea @ (I + 0.5*Wo@W_mo@Wiv@Wv)^T + 0.5*c
// ---------------------------------------------------------------------------
extern "C" void kernel_launch(void* const* d_in, const int* in_sizes, int n_in,
                              void* d_out, int out_size, void* d_ws, size_t ws_size,
                              hipStream_t stream) {
    const float* Wv   = (const float*)d_in[7];
    const float* bv   = (const float*)d_in[8];
    const float* W_in = (const float*)d_in[9];
    const float* b_in = (const float*)d_in[10];
    const float* W_mo = (const float*)d_in[11];
    const float* b_mo = (const float*)d_in[12];
    const float* Wo   = (const float*)d_in[13];
    const float* bo   = (const float*)d_in[14];
    const float* Wiv  = W_in + 2 * HID * HID;   // value third of packed in-proj
    const float* biv  = b_in + 2 * HID;

    char* ws = (char*)d_ws;
    float*          Pl = (float*)(ws);                    // 64 KB
    float*          Pr = (float*)(ws + 65536);            // 64 KB
    __hip_bfloat16* Mb = (__hip_bfloat16*)(ws + 131072);  // 32 KB
    float*          cv = (float*)(ws + 163840);           // 512 B

    const int E = in_sizes[0] / HID;
    const int numTiles = (E + 15) / 16;
    const int grid = numTiles < 2048 ? numTiles : 2048;

    prep_products<<<dim3(257), dim3(HID), 0, stream>>>(
        Wo, W_mo, Wiv, Wv, bv, biv, b_mo, bo, Pl, Pr, cv);
    prep_final<<<dim3(HID), dim3(HID), 0, stream>>>(Pl, Pr, Mb);

    edge_gemm<<<dim3(grid), dim3(256), 0, stream>>>(
        (const float*)d_in[0], Mb, cv, (float*)d_out, E, numTiles);
}